// Round 15
// baseline (508.612 us; speedup 1.0000x reference)
//
#include <hip/hip_runtime.h>
#include <hip/hip_bf16.h>

#define NN 10000
#define EE 160000
#define CCH 4
#define CF 16
#define RR 7
#define HH 256
#define NSEG 70000           // N*R
#define SCB 274              // ceil(NSEG/256)
#define EPSV 1e-5f

typedef unsigned short ushort_t;
typedef __bf16 bf16x8 __attribute__((ext_vector_type(8)));
typedef float f32x4 __attribute__((ext_vector_type(4)));

__device__ __forceinline__ float silu_f(float v) {
    float e = __builtin_amdgcn_exp2f(v * -1.442695040888963f);
    return v * __builtin_amdgcn_rcpf(1.f + e);
}

// manual RNE f32->bf16: wins in the VALU-saturated edge kernel (R12: 126->115us)
__device__ __forceinline__ ushort_t bf16u_m(float f) {
    unsigned int u = __builtin_bit_cast(unsigned int, f);
    u += 0x7fffu + ((u >> 16) & 1u);
    return (ushort_t)(u >> 16);
}

// native cvt RNE elsewhere
__device__ __forceinline__ ushort_t bf16u_n(float f) {
    return __builtin_bit_cast(ushort_t, (__bf16)f);
}

__device__ __forceinline__ float ubf2f(ushort_t u) {
    unsigned int v = ((unsigned int)u) << 16;
    return __builtin_bit_cast(float, v);
}

// ---------------- weight-pack helpers (device) ----------

__device__ __forceinline__ void pack_tile(
    const float* __restrict__ W, ushort_t* __restrict__ out,
    int Kreal, int N, int kt, int nt, int NTOT, int lane)
{
    int n = nt * 16 + (lane & 15);
    int kbase = kt * 32 + (lane >> 4) * 8;
    ushort_t* o = out + ((size_t)(kt * NTOT + nt) * 64 + lane) * 8;
    #pragma unroll
    for (int j = 0; j < 8; ++j) {
        int k = kbase + j;
        o[j] = (k < Kreal) ? bf16u_n(W[(size_t)k * N + n]) : (ushort_t)0;
    }
}

__device__ __forceinline__ void pack_ab_tile(
    const float* __restrict__ W_e1, ushort_t* __restrict__ pab,
    int kt, int nt, int lane)
{
    int nl = nt * 16 + (lane & 15);       // 0..511
    int kbase = kt * 32 + (lane >> 4) * 8;
    ushort_t* o = pab + ((size_t)(kt * 32 + nt) * 64 + lane) * 8;
    #pragma unroll
    for (int j = 0; j < 8; ++j) {
        int k = kbase + j;
        float v = 0.f;
        if (k < 256) {
            v = (nl < 256) ? W_e1[(size_t)k * 256 + nl]
                           : W_e1[(size_t)(256 + k) * 256 + (nl - 256)];
        } else if (k < 272) {
            int kk = k - 256;
            v = (nl < 256) ? W_e1[(size_t)(528 + kk) * 256 + nl]
                           : W_e1[(size_t)(544 + kk) * 256 + (nl - 256)];
        }
        o[j] = bf16u_n(v);
    }
}

__device__ __forceinline__ void pack_e1c_tile(
    const float* __restrict__ W_e1, ushort_t* __restrict__ pe1c,
    int nt, int lane)
{
    int n = nt * 16 + (lane & 15);
    int kbase = (lane >> 4) * 8;
    ushort_t* o = pe1c + ((size_t)nt * 64 + lane) * 8;
    #pragma unroll
    for (int j = 0; j < 8; ++j) {
        int k = kbase + j;
        o[j] = (k < 16) ? bf16u_n(W_e1[(size_t)(512 + k) * 256 + n]) : (ushort_t)0;
    }
}

__device__ __forceinline__ void pack_dispatch(
    int c, int lane,
    const float* __restrict__ W_e1, const float* __restrict__ W_e2,
    const float* __restrict__ W_c1, const float* __restrict__ W_c2,
    const float* __restrict__ W_n1, const float* __restrict__ W_n2,
    ushort_t* __restrict__ pab, ushort_t* __restrict__ pe1c,
    ushort_t* __restrict__ pe2,
    ushort_t* __restrict__ pc1, ushort_t* __restrict__ pc2,
    ushort_t* __restrict__ pn1, ushort_t* __restrict__ pn2)
{
    int l = 0;
    if (c >= 1720) { l = 1; c -= 1720; }
    const float* We1 = W_e1 + (size_t)l * 143360;
    if (c < 288) {
        pack_ab_tile(We1, pab + (size_t)l * 147456, c / 32, c % 32, lane);
    } else if (c < 304) {
        pack_e1c_tile(We1, pe1c + (size_t)l * 8192, c - 288, lane);
    } else if (c < 432) {
        int d = c - 304;
        pack_tile(W_e2 + (size_t)l * 65536, pe2 + (size_t)l * 65536,
                  256, 256, d / 16, d & 15, 16, lane);
    } else if (c < 560) {
        int d = c - 432;
        pack_tile(W_c1 + (size_t)l * 65536, pc1 + (size_t)l * 65536,
                  256, 256, d / 16, d & 15, 16, lane);
    } else if (c < 568) {
        int d = c - 560;
        pack_tile(W_c2 + (size_t)l * 4096, pc2 + (size_t)l * 4096,
                  256, 16, d, 0, 1, lane);
    } else if (c < 1592) {
        int d = c - 568;
        pack_tile(W_n1 + (size_t)l * 524288, pn1 + (size_t)l * 524288,
                  2048, 256, d / 16, d & 15, 16, lane);
    } else {
        int d = c - 1592;
        pack_tile(W_n2 + (size_t)l * 65536, pn2 + (size_t)l * 65536,
                  256, 256, d / 16, d & 15, 16, lane);
    }
}

// ---------------- fused prep kernel (zeros + cvt + cab + all packs) ----------
// blocks: [0,10000) cvt h; [10000,10625) cab; [10625,10899) zero hist;
// [10899,11173) zero cursor; [11173,11213) zero deg; [11213,11682) zero xacc;
// [11682,12542) weight packs (4 x 64-lane tiles per block, 3440 tiles).

__global__ __launch_bounds__(256) void prep_kernel(
    const float* __restrict__ input, ushort_t* __restrict__ hb16,
    const float* __restrict__ attr, const float* __restrict__ cw,
    ushort_t* __restrict__ cab16,
    int* __restrict__ hist, int* __restrict__ cursor,
    float* __restrict__ deg, float* __restrict__ xacc,
    const float* __restrict__ W_e1, const float* __restrict__ W_e2,
    const float* __restrict__ W_c1, const float* __restrict__ W_c2,
    const float* __restrict__ W_n1, const float* __restrict__ W_n2,
    ushort_t* __restrict__ pab, ushort_t* __restrict__ pe1c,
    ushort_t* __restrict__ pe2,
    ushort_t* __restrict__ pc1, ushort_t* __restrict__ pc2,
    ushort_t* __restrict__ pn1, ushort_t* __restrict__ pn2)
{
    int b = blockIdx.x, tid = threadIdx.x;
    if (b < 10000) {
        int t = b * 256 + tid;                 // exactly 2,560,000
        hb16[t] = bf16u_n(input[t]);
    } else if (b < 10625) {
        int t = (b - 10000) * 256 + tid;       // exactly 160,000
        int n = t >> 4, f = t & 15;
        float s = 0.f, cs = 0.f;
        #pragma unroll
        for (int c = 0; c < CCH; ++c) {
            float w = cw[n * CCH + c];
            s  += attr[(n * CCH + c) * CF + f] * w;
            cs += w;
        }
        cab16[t] = bf16u_n(s / cs);
    } else if (b < 10899) {
        int t = (b - 10625) * 256 + tid;
        if (t < NSEG) hist[t] = 0;
    } else if (b < 11173) {
        int t = (b - 10899) * 256 + tid;
        if (t < NSEG) cursor[t] = 0;
    } else if (b < 11213) {
        int t = (b - 11173) * 256 + tid;
        if (t < NN) deg[t] = 0.f;
    } else if (b < 11682) {
        int t = (b - 11213) * 256 + tid;
        if (t < NN * 12) xacc[t] = 0.f;
    } else {
        int c = (b - 11682) * 4 + (tid >> 6);  // 3440 tiles
        pack_dispatch(c, tid & 63, W_e1, W_e2, W_c1, W_c2, W_n1, W_n2,
                      pab, pe1c, pe2, pc1, pc2, pn1, pn2);
    }
}

__global__ __launch_bounds__(256) void histdeg_kernel(
    const int* __restrict__ el, int* __restrict__ hist, float* __restrict__ deg)
{
    int e = blockIdx.x * 256 + threadIdx.x;
    if (e < EE) {
        int r = el[e * 3], c = el[e * 3 + 1], rl = el[e * 3 + 2];
        atomicAdd(&hist[c * RR + rl], 1);
        atomicAdd(&deg[r], 1.f);
    }
}

__global__ __launch_bounds__(256) void scan1_kernel(
    const int* __restrict__ hist, int* __restrict__ pscan, int* __restrict__ bsum)
{
    __shared__ int sc[256];
    int b = blockIdx.x, t = threadIdx.x, i = b * 256 + t;
    int v = (i < NSEG) ? hist[i] : 0;
    sc[t] = v; __syncthreads();
    for (int off = 1; off < 256; off <<= 1) {
        int u = (t >= off) ? sc[t - off] : 0;
        __syncthreads();
        sc[t] += u;
        __syncthreads();
    }
    if (i < NSEG) pscan[i] = sc[t] - v;
    if (t == 255) bsum[b] = sc[255];
}

__global__ __launch_bounds__(256) void scan2_kernel(
    const int* __restrict__ bsum, int* __restrict__ bofs, int nb)
{
    __shared__ int sc[512];
    int t = threadIdx.x;
    int o1 = (t < nb) ? bsum[t] : 0;
    int o2 = (t + 256 < nb) ? bsum[t + 256] : 0;
    sc[t] = o1; sc[t + 256] = o2;
    __syncthreads();
    for (int off = 1; off < 512; off <<= 1) {
        int u1 = (t >= off) ? sc[t - off] : 0;
        int u2 = (t + 256 >= off) ? sc[t + 256 - off] : 0;
        __syncthreads();
        sc[t] += u1; sc[t + 256] += u2;
        __syncthreads();
    }
    if (t < nb) bofs[t] = sc[t] - o1;
    if (t + 256 < nb) bofs[t + 256] = sc[t + 256] - o2;
}

__global__ __launch_bounds__(256) void scan3_kernel(
    const int* __restrict__ pscan, const int* __restrict__ bofs, int* __restrict__ segst)
{
    int b = blockIdx.x, t = threadIdx.x, i = b * 256 + t;
    if (i < NSEG) segst[i] = pscan[i] + bofs[b];
    if (i == 0) segst[NSEG] = EE;
}

__global__ __launch_bounds__(256) void scatter_kernel(
    const int* __restrict__ el, const int* __restrict__ segst,
    int* __restrict__ cursor, int* __restrict__ perm)
{
    int e = blockIdx.x * 256 + threadIdx.x;
    if (e < EE) {
        int s = el[e * 3 + 1] * RR + el[e * 3 + 2];
        int pos = segst[s] + atomicAdd(&cursor[s], 1);
        perm[pos] = e;
    }
}

// ---------------- A/B node-partial precompute --------------------------------

__global__ __launch_bounds__(256, 3) void abk_kernel(
    const ushort_t* __restrict__ hb16, const ushort_t* __restrict__ cab16,
    const ushort_t* __restrict__ pab, const float* __restrict__ b_e1,
    ushort_t* __restrict__ A16, ushort_t* __restrict__ B16)
{
    __shared__ ushort_t inbuf[32][296];
    __shared__ ushort_t obuf[32][520];
    const int tid = threadIdx.x, lane = tid & 63, w = tid >> 6;
    const int ar = lane & 15, aq = (lane >> 4) * 8, quad = lane >> 4;
    const int n0 = blockIdx.x * 32;
    const uint4 z4 = {0u, 0u, 0u, 0u};

    #pragma unroll
    for (int it = 0; it < 4; ++it) {
        int c = it * 256 + tid;
        int e = c >> 5, i4 = c & 31;
        int node = n0 + e;
        uint4 v = (node < NN) ? ((const uint4*)(hb16 + (size_t)node * 256))[i4] : z4;
        *(uint4*)&inbuf[e][i4 * 8] = v;
    }
    if (tid < 64) {
        int e = tid >> 1, i4 = tid & 1;
        int node = n0 + e;
        uint4 v = (node < NN) ? ((const uint4*)(cab16 + node * 16))[i4] : z4;
        *(uint4*)&inbuf[e][256 + i4 * 8] = v;
    } else if (tid < 128) {
        int c = tid - 64, e = c >> 1, i4 = c & 1;
        *(uint4*)&inbuf[e][272 + i4 * 8] = z4;
    }
    __syncthreads();

    const f32x4 Z = {0.f, 0.f, 0.f, 0.f};
    f32x4 acc[2][8];
    #pragma unroll
    for (int mt = 0; mt < 2; ++mt)
        #pragma unroll
        for (int jt = 0; jt < 8; ++jt) acc[mt][jt] = Z;
    for (int kt = 0; kt < 9; ++kt) {
        bf16x8 a0 = *(const bf16x8*)&inbuf[ar][kt * 32 + aq];
        bf16x8 a1 = *(const bf16x8*)&inbuf[16 + ar][kt * 32 + aq];
        #pragma unroll
        for (int jt = 0; jt < 8; ++jt) {
            bf16x8 b = *(const bf16x8*)(pab + ((size_t)(kt * 32 + w * 8 + jt) * 64 + lane) * 8);
            acc[0][jt] = __builtin_amdgcn_mfma_f32_16x16x32_bf16(a0, b, acc[0][jt], 0, 0, 0);
            acc[1][jt] = __builtin_amdgcn_mfma_f32_16x16x32_bf16(a1, b, acc[1][jt], 0, 0, 0);
        }
    }
    #pragma unroll
    for (int jt = 0; jt < 8; ++jt) {
        int n = w * 128 + jt * 16 + ar;
        float bias = (n < 256) ? b_e1[n] : 0.f;
        #pragma unroll
        for (int mt = 0; mt < 2; ++mt)
            #pragma unroll
            for (int r = 0; r < 4; ++r)
                obuf[mt * 16 + quad * 4 + r][n] = bf16u_n(acc[mt][jt][r] + bias);
    }
    __syncthreads();
    #pragma unroll
    for (int it = 0; it < 8; ++it) {
        int c = it * 256 + tid;
        int e = c >> 6, i4 = c & 63;
        int node = n0 + e;
        if (node < NN) {
            if (i4 < 32)
                *(uint4*)(A16 + (size_t)node * 256 + i4 * 8) = *(const uint4*)&obuf[e][i4 * 8];
            else
                *(uint4*)(B16 + (size_t)node * 256 + (i4 - 32) * 8) = *(const uint4*)&obuf[e][256 + (i4 - 32) * 8];
        }
    }
}

// ---------------- MFMA stage helper (32-edge M-tile) ----------------

template<int KT, int NTOT>
__device__ __forceinline__ void mfma_stage32(
    const ushort_t (&A)[32][584], int colOff,
    const ushort_t* __restrict__ Wp, int w, int lane,
    f32x4 (&acc)[2][4])
{
    const f32x4 Z = {0.f, 0.f, 0.f, 0.f};
    #pragma unroll
    for (int mt = 0; mt < 2; ++mt)
        #pragma unroll
        for (int j = 0; j < 4; ++j) acc[mt][j] = Z;
    const int ar = lane & 15, aq = (lane >> 4) * 8;
    for (int kt = 0; kt < KT; ++kt) {
        bf16x8 a0 = *(const bf16x8*)&A[ar][colOff + kt * 32 + aq];
        bf16x8 a1 = *(const bf16x8*)&A[16 + ar][colOff + kt * 32 + aq];
        #pragma unroll
        for (int j = 0; j < 4; ++j) {
            bf16x8 b = *(const bf16x8*)(Wp + ((size_t)(kt * NTOT + w * 4 + j) * 64 + lane) * 8);
            acc[0][j] = __builtin_amdgcn_mfma_f32_16x16x32_bf16(a0, b, acc[0][j], 0, 0, 0);
            acc[1][j] = __builtin_amdgcn_mfma_f32_16x16x32_bf16(a1, b, acc[1][j], 0, 0, 0);
        }
    }
}

// ---------------- fused edge kernel (32 sorted edges/block, 4 blk/CU) ----------

__global__ __launch_bounds__(256, 4) void edge_kernel(
    const int* __restrict__ el, const int* __restrict__ perm,
    const float* __restrict__ cw,
    const float* __restrict__ ew, const float* __restrict__ x,
    const ushort_t* __restrict__ A16, const ushort_t* __restrict__ B16,
    const float* __restrict__ W_rad, const float* __restrict__ b_rad,
    const ushort_t* __restrict__ pe1c,
    const ushort_t* __restrict__ pe2, const float* __restrict__ b_e2,
    const ushort_t* __restrict__ pc1, const float* __restrict__ b_c1,
    const ushort_t* __restrict__ pc2,
    ushort_t* __restrict__ mb16, float* __restrict__ xacc)
{
    // X = cols 0..255 (rad_feat in 0..31, later m), Y = cols 288..543 (S/t1/t2)
    __shared__ ushort_t abuf[32][584];
    __shared__ float radbuf[32][16];
    __shared__ int rowS[32], colS[32];
    __shared__ float ewS[32];

    const int tid = threadIdx.x, lane = tid & 63, w = tid >> 6;
    const int ar = lane & 15, aq = (lane >> 4) * 8, quad = lane >> 4;
    const int e0 = blockIdx.x * 32;

    if (tid < 32) {
        int eg = perm[e0 + tid];
        rowS[tid] = el[eg * 3 + 0];
        colS[tid] = el[eg * 3 + 1];
        ewS[tid]  = ew[eg];
    }
    __syncthreads();   // B1

    // ---- staging: S = A[row] + B[col] -> Y, radial -> radbuf ----
    #pragma unroll
    for (int it = 0; it < 4; ++it) {
        int c = it * 256 + tid;
        int e = c >> 5, i4 = c & 31;
        bf16x8 va = *(const bf16x8*)((const uint4*)(A16 + (size_t)rowS[e] * 256) + i4);
        bf16x8 vb = *(const bf16x8*)((const uint4*)(B16 + (size_t)colS[e] * 256) + i4);
        bf16x8 vs;
        #pragma unroll
        for (int j = 0; j < 8; ++j)
            vs[j] = (__bf16)((float)va[j] + (float)vb[j]);
        *(bf16x8*)&abuf[e][288 + i4 * 8] = vs;
    }
    #pragma unroll
    for (int it = 0; it < 2; ++it) {
        int t = it * 256 + tid;
        int e = t >> 4, ab = t & 15, a = ab >> 2, b = ab & 3;
        int row = rowS[e], col = colS[e];
        float d0 = x[row * 12 + a * 3 + 0] - x[col * 12 + b * 3 + 0];
        float d1 = x[row * 12 + a * 3 + 1] - x[col * 12 + b * 3 + 1];
        float d2 = x[row * 12 + a * 3 + 2] - x[col * 12 + b * 3 + 2];
        radbuf[e][ab] = (d0 * d0 + d1 * d1 + d2 * d2)
                      * cw[row * CCH + a] * cw[col * CCH + b];
    }
    __syncthreads();   // B2

    // rad_feat -> X cols 0..15, zero pad 16..31
    #pragma unroll
    for (int it = 0; it < 2; ++it) {
        int t = it * 256 + tid;
        int e = t >> 4, f = t & 15;
        float acc = b_rad[f];
        #pragma unroll
        for (int ab = 0; ab < 16; ++ab) acc += radbuf[e][ab] * W_rad[ab * 16 + f];
        abuf[e][f] = bf16u_m(silu_f(acc));
        abuf[e][16 + f] = 0;
    }
    __syncthreads();   // B3

    f32x4 acc[2][4];

    // ---- e1 residual: rad_feat @ W1c (KT=1), t1 = silu(S + acc) ----
    mfma_stage32<1, 16>(abuf, 0, pe1c, w, lane, acc);
    #pragma unroll
    for (int j = 0; j < 4; ++j) {
        int n = w * 64 + j * 16 + ar;
        #pragma unroll
        for (int mt = 0; mt < 2; ++mt)
            #pragma unroll
            for (int r = 0; r < 4; ++r) {
                int e = mt * 16 + quad * 4 + r;
                float s = ubf2f(abuf[e][288 + n]) + acc[mt][j][r];
                abuf[e][288 + n] = bf16u_m(silu_f(s));
            }
    }
    __syncthreads();   // B4

    // ---- e2: reads Y, writes m -> X ----
    mfma_stage32<8, 16>(abuf, 288, pe2, w, lane, acc);
    #pragma unroll
    for (int j = 0; j < 4; ++j) {
        int n = w * 64 + j * 16 + ar;
        float bj = b_e2[n];
        #pragma unroll
        for (int mt = 0; mt < 2; ++mt)
            #pragma unroll
            for (int r = 0; r < 4; ++r) {
                int e = mt * 16 + quad * 4 + r;
                abuf[e][n] = bf16u_m(silu_f(acc[mt][j][r] + bj) * ewS[e]);
            }
    }
    __syncthreads();   // B5

    // ---- store m rows to mb16 ----
    #pragma unroll
    for (int it = 0; it < 4; ++it) {
        int t = it * 256 + tid;
        int e = t >> 5, c = t & 31;
        *(uint4*)(mb16 + ((size_t)(e0 + e) * 256 + c * 8)) =
            *(const uint4*)&abuf[e][c * 8];
    }

    // ---- c1: reads X, writes t2 -> Y ----
    mfma_stage32<8, 16>(abuf, 0, pc1, w, lane, acc);
    #pragma unroll
    for (int j = 0; j < 4; ++j) {
        int n = w * 64 + j * 16 + ar;
        float bj = b_c1[n];
        #pragma unroll
        for (int mt = 0; mt < 2; ++mt)
            #pragma unroll
            for (int r = 0; r < 4; ++r)
                abuf[mt * 16 + quad * 4 + r][288 + n] = bf16u_m(silu_f(acc[mt][j][r] + bj));
    }
    __syncthreads();   // B6

    // ---- c2: waves 0,1 -> phi -> radbuf ----
    if (w < 2) {
        const f32x4 Z = {0.f, 0.f, 0.f, 0.f};
        f32x4 p = Z;
        #pragma unroll
        for (int kt = 0; kt < 8; ++kt) {
            bf16x8 a = *(const bf16x8*)&abuf[w * 16 + ar][288 + kt * 32 + aq];
            bf16x8 b = *(const bf16x8*)(pc2 + ((size_t)kt * 64 + lane) * 8);
            p = __builtin_amdgcn_mfma_f32_16x16x32_bf16(a, b, p, 0, 0, 0);
        }
        #pragma unroll
        for (int r = 0; r < 4; ++r)
            radbuf[w * 16 + quad * 4 + r][ar] = p[r];
    }
    __syncthreads();   // B7

    // ---- trans -> xacc ----
    for (int t = tid; t < 384; t += 256) {
        int e = t / 12, r = t - e * 12, a = r / 3, k = r - a * 3;
        int row = rowS[e], col = colS[e];
        float xr = x[row * 12 + a * 3 + k];
        float s = 0.f;
        #pragma unroll
        for (int b = 0; b < 4; ++b)
            s += (xr - x[col * 12 + b * 3 + k]) * radbuf[e][a * 4 + b];
        atomicAdd(&xacc[row * 12 + a * 3 + k], 0.25f * s);
    }
}

// ---------------- fused node kernel (segsum + n1 + n2 + LN + xout) ----
// LDS diet: tbuf/h2buf union into the nbuf arena -> 35.2 KB -> 4 blocks/CU.
// Safety: nbuf's last read is before the chunk-loop's closing barrier; tbuf
// (arena+0) written only after it. tbuf reads (n2 loop) overlap h2buf writes
// (arena+8448) but the regions are disjoint.

__global__ __launch_bounds__(256, 4) void node_kernel(
    const ushort_t* __restrict__ mb16, const int* __restrict__ segst,
    const ushort_t* __restrict__ pn1, const float* __restrict__ b_n1,
    const ushort_t* __restrict__ pn2, const float* __restrict__ b_n2,
    const float* __restrict__ ln_g, const float* __restrict__ ln_b,
    float* __restrict__ h_out, ushort_t* __restrict__ hb16,
    const float* __restrict__ x_in, float* __restrict__ xacc,
    const float* __restrict__ deg, float* __restrict__ x_out)
{
    __shared__ __align__(16) char arena[33024];
    __shared__ float redS[16][16], red2S[16][16], muS[16], rsS[16];
    ushort_t (*nbuf)[1032] = (ushort_t(*)[1032])arena;
    ushort_t (*tbuf)[264] = (ushort_t(*)[264])arena;             // 8448 B
    float (*h2buf)[264] = (float(*)[264])(arena + 8448);         // 16896 B

    const int tid = threadIdx.x, lane = tid & 63, w = tid >> 6;
    const int n0 = blockIdx.x * 16;
    const int ar = lane & 15, aq = (lane >> 4) * 8;
    const f32x4 Z = {0.f, 0.f, 0.f, 0.f};

    // ---- xout + xacc re-zero for next layer ----
    if (tid < 192) {
        int ln = tid / 12, r = tid - ln * 12;
        int n = n0 + ln;
        float c = fmaxf(deg[n], 1.f);
        x_out[n * 12 + r] = x_in[n * 12 + r] + xacc[n * 12 + r] / c;
        xacc[n * 12 + r] = 0.f;
    }

    f32x4 acc[4] = {Z, Z, Z, Z};
    for (int chunk = 0; chunk < 2; ++chunk) {
        for (int ln = 0; ln < 4; ++ln) {
            int node = w * 4 + ln;
            int gnode = n0 + node;
            if (chunk == 0) {
                #pragma unroll
                for (int r = 0; r < 4; ++r) {
                    int s = gnode * RR + r;
                    int beg = segst[s], end = segst[s + 1];
                    float a0 = 0.f, a1 = 0.f, a2 = 0.f, a3 = 0.f;
                    for (int e = beg; e < end; ++e) {
                        ushort4 u = *(const ushort4*)(mb16 + (size_t)e * 256 + lane * 4);
                        a0 += ubf2f(u.x); a1 += ubf2f(u.y);
                        a2 += ubf2f(u.z); a3 += ubf2f(u.w);
                    }
                    ushort4 o;
                    o.x = bf16u_n(a0); o.y = bf16u_n(a1); o.z = bf16u_n(a2); o.w = bf16u_n(a3);
                    *(ushort4*)&nbuf[node][r * 256 + lane * 4] = o;
                }
            } else {
                #pragma unroll
                for (int r = 4; r < 7; ++r) {
                    int s = gnode * RR + r;
                    int beg = segst[s], end = segst[s + 1];
                    float a0 = 0.f, a1 = 0.f, a2 = 0.f, a3 = 0.f;
                    for (int e = beg; e < end; ++e) {
                        ushort4 u = *(const ushort4*)(mb16 + (size_t)e * 256 + lane * 4);
                        a0 += ubf2f(u.x); a1 += ubf2f(u.y);
                        a2 += ubf2f(u.z); a3 += ubf2f(u.w);
                    }
                    ushort4 o;
                    o.x = bf16u_n(a0); o.y = bf16u_n(a1); o.z = bf16u_n(a2); o.w = bf16u_n(a3);
                    *(ushort4*)&nbuf[node][(r - 4) * 256 + lane * 4] = o;
                }
                *(ushort4*)&nbuf[node][768 + lane * 4] =
                    *(const ushort4*)(hb16 + (size_t)gnode * 256 + lane * 4);
            }
        }
        __syncthreads();
        for (int kt = 0; kt < 32; ++kt) {
            bf16x8 a = *(const bf16x8*)&nbuf[ar][kt * 32 + aq];
            int ktg = chunk * 32 + kt;
            #pragma unroll
            for (int j = 0; j < 4; ++j) {
                bf16x8 b = *(const bf16x8*)(pn1 + ((size_t)(ktg * 16 + w * 4 + j) * 64 + lane) * 8);
                acc[j] = __builtin_amdgcn_mfma_f32_16x16x32_bf16(a, b, acc[j], 0, 0, 0);
            }
        }
        __syncthreads();
    }
    // tbuf aliases the (now-dead) nbuf region; barrier above protects it.
    #pragma unroll
    for (int j = 0; j < 4; ++j) {
        int n = w * 64 + j * 16 + ar;
        float bj = b_n1[n];
        #pragma unroll
        for (int r = 0; r < 4; ++r)
            tbuf[(lane >> 4) * 4 + r][n] = bf16u_n(silu_f(acc[j][r] + bj));
    }
    __syncthreads();
    f32x4 acc2[4] = {Z, Z, Z, Z};
    for (int kt = 0; kt < 8; ++kt) {
        bf16x8 a = *(const bf16x8*)&tbuf[ar][kt * 32 + aq];
        #pragma unroll
        for (int j = 0; j < 4; ++j) {
            bf16x8 b = *(const bf16x8*)(pn2 + ((size_t)(kt * 16 + w * 4 + j) * 64 + lane) * 8);
            acc2[j] = __builtin_amdgcn_mfma_f32_16x16x32_bf16(a, b, acc2[j], 0, 0, 0);
        }
    }
    float hv[4][4];
    #pragma unroll
    for (int j = 0; j < 4; ++j) {
        int n = w * 64 + j * 16 + ar;
        float bj = b_n2[n];
        #pragma unroll
        for (int r = 0; r < 4; ++r) {
            hv[j][r] = acc2[j][r] + bj;
            h2buf[(lane >> 4) * 4 + r][n] = hv[j][r];
        }
    }
    __syncthreads();
    {
        int node = tid >> 4, c = tid & 15;
        float s = 0.f, s2 = 0.f;
        #pragma unroll
        for (int i = 0; i < 16; ++i) {
            float v = h2buf[node][c * 16 + i];
            s += v; s2 += v * v;
        }
        redS[node][c] = s; red2S[node][c] = s2;
    }
    __syncthreads();
    if (tid < 16) {
        float s = 0.f, s2 = 0.f;
        #pragma unroll
        for (int c = 0; c < 16; ++c) { s += redS[tid][c]; s2 += red2S[tid][c]; }
        float mu = s * (1.f / 256.f);
        muS[tid] = mu;
        rsS[tid] = rsqrtf(s2 * (1.f / 256.f) - mu * mu + EPSV);
    }
    __syncthreads();
    #pragma unroll
    for (int j = 0; j < 4; ++j) {
        int n = w * 64 + j * 16 + ar;
        float g = ln_g[n], bb = ln_b[n];
        #pragma unroll
        for (int r = 0; r < 4; ++r) {
            int row = (lane >> 4) * 4 + r;
            float v = (hv[j][r] - muS[row]) * rsS[row] * g + bb;
            if (h_out) h_out[(size_t)(n0 + row) * HH + n] = v;
            hb16[(size_t)(n0 + row) * HH + n] = bf16u_n(v);
        }
    }
}

// ---------------- launcher ----------------

extern "C" void kernel_launch(void* const* d_in, const int* in_sizes, int n_in,
                              void* d_out, int out_size, void* d_ws, size_t ws_size,
                              hipStream_t stream)
{
    const float* input  = (const float*)d_in[0];
    const float* coords = (const float*)d_in[1];
    const float* cattr  = (const float*)d_in[2];
    const float* cwts   = (const float*)d_in[3];
    const float* ewts   = (const float*)d_in[4];
    const int*   elist  = (const int*)d_in[5];
    const float* W_rad  = (const float*)d_in[6];
    const float* b_rad  = (const float*)d_in[7];
    const float* W_e1   = (const float*)d_in[8];
    const float* b_e1   = (const float*)d_in[9];
    const float* W_e2   = (const float*)d_in[10];
    const float* b_e2   = (const float*)d_in[11];
    const float* W_c1   = (const float*)d_in[12];
    const float* b_c1   = (const float*)d_in[13];
    const float* W_c2   = (const float*)d_in[14];
    const float* W_n1   = (const float*)d_in[15];
    const float* b_n1   = (const float*)d_in[16];
    const float* W_n2   = (const float*)d_in[17];
    const float* b_n2   = (const float*)d_in[18];
    const float* ln_g   = (const float*)d_in[19];
    const float* ln_b   = (const float*)d_in[20];

    float* wsf  = (float*)d_ws;
    float* deg  = wsf;                    // 10000
    float* xacc = deg + 10000;            // 120000
    float* xbuf = xacc + 120000;          // 120000
    int* ip     = (int*)(xbuf + 120000);
    int* hist   = ip;                     // 70000
    int* pscan  = hist + 70000;           // 70000
    int* cursor = pscan + 70000;          // 70000
    int* segst  = cursor + 70000;         // 70001
    int* bsum   = segst + 70001;          // 512
    int* bofs   = bsum + 512;             // 512
    int* perm   = bofs + 512;             // 160000
    ushort_t* up = (ushort_t*)(((uintptr_t)(perm + 160000) + 15) & ~(uintptr_t)15);
    ushort_t* hb16  = up;                 // 2,560,000
    ushort_t* cab16 = hb16 + 2560000;     // 160,000
    ushort_t* mb16  = cab16 + 160000;     // 40,960,000
    ushort_t* A16   = mb16 + 40960000;    // 2,560,000
    ushort_t* B16   = A16 + 2560000;      // 2,560,000
    ushort_t* pab   = B16 + 2560000;      // 2 x 147456
    ushort_t* pe1c  = pab + 294912;       // 2 x 8192
    ushort_t* pe2   = pe1c + 16384;       // 2 x 65536
    ushort_t* pc1   = pe2 + 131072;       // 2 x 65536
    ushort_t* pc2   = pc1 + 131072;       // 2 x 4096
    ushort_t* pn1   = pc2 + 8192;         // 2 x 524288
    ushort_t* pn2   = pn1 + 1048576;      // 2 x 65536

    prep_kernel<<<12542, 256, 0, stream>>>(
        input, hb16, cattr, cwts, cab16, hist, cursor, deg, xacc,
        W_e1, W_e2, W_c1, W_c2, W_n1, W_n2,
        pab, pe1c, pe2, pc1, pc2, pn1, pn2);

    histdeg_kernel<<<(EE + 255) / 256, 256, 0, stream>>>(elist, hist, deg);
    scan1_kernel<<<SCB, 256, 0, stream>>>(hist, pscan, bsum);
    scan2_kernel<<<1, 256, 0, stream>>>(bsum, bofs, SCB);
    scan3_kernel<<<SCB, 256, 0, stream>>>(pscan, bofs, segst);
    scatter_kernel<<<(EE + 255) / 256, 256, 0, stream>>>(elist, segst, cursor, perm);

    for (int l = 0; l < 2; ++l) {
        const float* x_in = (l == 0) ? coords : xbuf;
        float* h_out = (l == 0) ? nullptr : (float*)d_out;  // layer0 fp32 h never read
        float* x_out = (l == 0) ? xbuf : ((float*)d_out + (size_t)NN * HH);

        abk_kernel<<<(NN + 31) / 32, 256, 0, stream>>>(
            hb16, cab16, pab + (size_t)l * 147456, b_e1 + l * HH, A16, B16);

        edge_kernel<<<EE / 32, 256, 0, stream>>>(
            elist, perm, cwts, ewts, x_in, A16, B16,
            W_rad + l * 256, b_rad + l * 16,
            pe1c + (size_t)l * 8192,
            pe2 + (size_t)l * 65536,  b_e2 + l * HH,
            pc1 + (size_t)l * 65536,  b_c1 + l * HH,
            pc2 + (size_t)l * 4096,
            mb16, xacc);

        node_kernel<<<NN / 16, 256, 0, stream>>>(
            mb16, segst,
            pn1 + (size_t)l * 524288, b_n1 + l * HH,
            pn2 + (size_t)l * 65536,  b_n2 + l * HH,
            ln_g + l * HH, ln_b + l * HH,
            h_out, hb16,
            x_in, xacc, deg, x_out);
    }
}

// Round 16
// 495.287 us; speedup vs baseline: 1.0269x; 1.0269x over previous
//
#include <hip/hip_runtime.h>
#include <hip/hip_bf16.h>

#define NN 10000
#define EE 160000
#define CCH 4
#define CF 16
#define RR 7
#define HH 256
#define NSEG 70000           // N*R
#define SCB 274              // ceil(NSEG/256)
#define EPSV 1e-5f

typedef unsigned short ushort_t;
typedef __bf16 bf16x8 __attribute__((ext_vector_type(8)));
typedef float f32x4 __attribute__((ext_vector_type(4)));

__device__ __forceinline__ float silu_f(float v) {
    float e = __builtin_amdgcn_exp2f(v * -1.442695040888963f);
    return v * __builtin_amdgcn_rcpf(1.f + e);
}

// manual RNE f32->bf16: wins in the VALU-saturated edge kernel (R12: 126->115us)
__device__ __forceinline__ ushort_t bf16u_m(float f) {
    unsigned int u = __builtin_bit_cast(unsigned int, f);
    u += 0x7fffu + ((u >> 16) & 1u);
    return (ushort_t)(u >> 16);
}

// native cvt RNE elsewhere
__device__ __forceinline__ ushort_t bf16u_n(float f) {
    return __builtin_bit_cast(ushort_t, (__bf16)f);
}

__device__ __forceinline__ float ubf2f(ushort_t u) {
    unsigned int v = ((unsigned int)u) << 16;
    return __builtin_bit_cast(float, v);
}

// ---------------- weight-pack helpers (device) ----------

__device__ __forceinline__ void pack_tile(
    const float* __restrict__ W, ushort_t* __restrict__ out,
    int Kreal, int N, int kt, int nt, int NTOT, int lane)
{
    int n = nt * 16 + (lane & 15);
    int kbase = kt * 32 + (lane >> 4) * 8;
    ushort_t* o = out + ((size_t)(kt * NTOT + nt) * 64 + lane) * 8;
    #pragma unroll
    for (int j = 0; j < 8; ++j) {
        int k = kbase + j;
        o[j] = (k < Kreal) ? bf16u_n(W[(size_t)k * N + n]) : (ushort_t)0;
    }
}

__device__ __forceinline__ void pack_ab_tile(
    const float* __restrict__ W_e1, ushort_t* __restrict__ pab,
    int kt, int nt, int lane)
{
    int nl = nt * 16 + (lane & 15);       // 0..511
    int kbase = kt * 32 + (lane >> 4) * 8;
    ushort_t* o = pab + ((size_t)(kt * 32 + nt) * 64 + lane) * 8;
    #pragma unroll
    for (int j = 0; j < 8; ++j) {
        int k = kbase + j;
        float v = 0.f;
        if (k < 256) {
            v = (nl < 256) ? W_e1[(size_t)k * 256 + nl]
                           : W_e1[(size_t)(256 + k) * 256 + (nl - 256)];
        } else if (k < 272) {
            int kk = k - 256;
            v = (nl < 256) ? W_e1[(size_t)(528 + kk) * 256 + nl]
                           : W_e1[(size_t)(544 + kk) * 256 + (nl - 256)];
        }
        o[j] = bf16u_n(v);
    }
}

__device__ __forceinline__ void pack_e1c_tile(
    const float* __restrict__ W_e1, ushort_t* __restrict__ pe1c,
    int nt, int lane)
{
    int n = nt * 16 + (lane & 15);
    int kbase = (lane >> 4) * 8;
    ushort_t* o = pe1c + ((size_t)nt * 64 + lane) * 8;
    #pragma unroll
    for (int j = 0; j < 8; ++j) {
        int k = kbase + j;
        o[j] = (k < 16) ? bf16u_n(W_e1[(size_t)(512 + k) * 256 + n]) : (ushort_t)0;
    }
}

__device__ __forceinline__ void pack_dispatch(
    int c, int lane,
    const float* __restrict__ W_e1, const float* __restrict__ W_e2,
    const float* __restrict__ W_c1, const float* __restrict__ W_c2,
    const float* __restrict__ W_n1, const float* __restrict__ W_n2,
    ushort_t* __restrict__ pab, ushort_t* __restrict__ pe1c,
    ushort_t* __restrict__ pe2,
    ushort_t* __restrict__ pc1, ushort_t* __restrict__ pc2,
    ushort_t* __restrict__ pn1, ushort_t* __restrict__ pn2)
{
    int l = 0;
    if (c >= 1720) { l = 1; c -= 1720; }
    const float* We1 = W_e1 + (size_t)l * 143360;
    if (c < 288) {
        pack_ab_tile(We1, pab + (size_t)l * 147456, c / 32, c % 32, lane);
    } else if (c < 304) {
        pack_e1c_tile(We1, pe1c + (size_t)l * 8192, c - 288, lane);
    } else if (c < 432) {
        int d = c - 304;
        pack_tile(W_e2 + (size_t)l * 65536, pe2 + (size_t)l * 65536,
                  256, 256, d / 16, d & 15, 16, lane);
    } else if (c < 560) {
        int d = c - 432;
        pack_tile(W_c1 + (size_t)l * 65536, pc1 + (size_t)l * 65536,
                  256, 256, d / 16, d & 15, 16, lane);
    } else if (c < 568) {
        int d = c - 560;
        pack_tile(W_c2 + (size_t)l * 4096, pc2 + (size_t)l * 4096,
                  256, 16, d, 0, 1, lane);
    } else if (c < 1592) {
        int d = c - 568;
        pack_tile(W_n1 + (size_t)l * 524288, pn1 + (size_t)l * 524288,
                  2048, 256, d / 16, d & 15, 16, lane);
    } else {
        int d = c - 1592;
        pack_tile(W_n2 + (size_t)l * 65536, pn2 + (size_t)l * 65536,
                  256, 256, d / 16, d & 15, 16, lane);
    }
}

// ---------------- fused prep kernel (zeros + cvt + cab + all packs) ----------

__global__ __launch_bounds__(256) void prep_kernel(
    const float* __restrict__ input, ushort_t* __restrict__ hb16,
    const float* __restrict__ attr, const float* __restrict__ cw,
    ushort_t* __restrict__ cab16,
    int* __restrict__ hist, int* __restrict__ cursor,
    float* __restrict__ deg, float* __restrict__ xacc,
    const float* __restrict__ W_e1, const float* __restrict__ W_e2,
    const float* __restrict__ W_c1, const float* __restrict__ W_c2,
    const float* __restrict__ W_n1, const float* __restrict__ W_n2,
    ushort_t* __restrict__ pab, ushort_t* __restrict__ pe1c,
    ushort_t* __restrict__ pe2,
    ushort_t* __restrict__ pc1, ushort_t* __restrict__ pc2,
    ushort_t* __restrict__ pn1, ushort_t* __restrict__ pn2)
{
    int b = blockIdx.x, tid = threadIdx.x;
    if (b < 10000) {
        int t = b * 256 + tid;                 // exactly 2,560,000
        hb16[t] = bf16u_n(input[t]);
    } else if (b < 10625) {
        int t = (b - 10000) * 256 + tid;       // exactly 160,000
        int n = t >> 4, f = t & 15;
        float s = 0.f, cs = 0.f;
        #pragma unroll
        for (int c = 0; c < CCH; ++c) {
            float w = cw[n * CCH + c];
            s  += attr[(n * CCH + c) * CF + f] * w;
            cs += w;
        }
        cab16[t] = bf16u_n(s / cs);
    } else if (b < 10899) {
        int t = (b - 10625) * 256 + tid;
        if (t < NSEG) hist[t] = 0;
    } else if (b < 11173) {
        int t = (b - 10899) * 256 + tid;
        if (t < NSEG) cursor[t] = 0;
    } else if (b < 11213) {
        int t = (b - 11173) * 256 + tid;
        if (t < NN) deg[t] = 0.f;
    } else if (b < 11682) {
        int t = (b - 11213) * 256 + tid;
        if (t < NN * 12) xacc[t] = 0.f;
    } else {
        int c = (b - 11682) * 4 + (tid >> 6);  // 3440 tiles
        pack_dispatch(c, tid & 63, W_e1, W_e2, W_c1, W_c2, W_n1, W_n2,
                      pab, pe1c, pe2, pc1, pc2, pn1, pn2);
    }
}

__global__ __launch_bounds__(256) void histdeg_kernel(
    const int* __restrict__ el, int* __restrict__ hist, float* __restrict__ deg)
{
    int e = blockIdx.x * 256 + threadIdx.x;
    if (e < EE) {
        int r = el[e * 3], c = el[e * 3 + 1], rl = el[e * 3 + 2];
        atomicAdd(&hist[c * RR + rl], 1);
        atomicAdd(&deg[r], 1.f);
    }
}

__global__ __launch_bounds__(256) void scan1_kernel(
    const int* __restrict__ hist, int* __restrict__ pscan, int* __restrict__ bsum)
{
    __shared__ int sc[256];
    int b = blockIdx.x, t = threadIdx.x, i = b * 256 + t;
    int v = (i < NSEG) ? hist[i] : 0;
    sc[t] = v; __syncthreads();
    for (int off = 1; off < 256; off <<= 1) {
        int u = (t >= off) ? sc[t - off] : 0;
        __syncthreads();
        sc[t] += u;
        __syncthreads();
    }
    if (i < NSEG) pscan[i] = sc[t] - v;
    if (t == 255) bsum[b] = sc[255];
}

__global__ __launch_bounds__(256) void scan2_kernel(
    const int* __restrict__ bsum, int* __restrict__ bofs, int nb)
{
    __shared__ int sc[512];
    int t = threadIdx.x;
    int o1 = (t < nb) ? bsum[t] : 0;
    int o2 = (t + 256 < nb) ? bsum[t + 256] : 0;
    sc[t] = o1; sc[t + 256] = o2;
    __syncthreads();
    for (int off = 1; off < 512; off <<= 1) {
        int u1 = (t >= off) ? sc[t - off] : 0;
        int u2 = (t + 256 >= off) ? sc[t + 256 - off] : 0;
        __syncthreads();
        sc[t] += u1; sc[t + 256] += u2;
        __syncthreads();
    }
    if (t < nb) bofs[t] = sc[t] - o1;
    if (t + 256 < nb) bofs[t + 256] = sc[t + 256] - o2;
}

__global__ __launch_bounds__(256) void scan3_kernel(
    const int* __restrict__ pscan, const int* __restrict__ bofs, int* __restrict__ segst)
{
    int b = blockIdx.x, t = threadIdx.x, i = b * 256 + t;
    if (i < NSEG) segst[i] = pscan[i] + bofs[b];
    if (i == 0) segst[NSEG] = EE;
}

__global__ __launch_bounds__(256) void scatter_kernel(
    const int* __restrict__ el, const int* __restrict__ segst,
    int* __restrict__ cursor, int* __restrict__ perm)
{
    int e = blockIdx.x * 256 + threadIdx.x;
    if (e < EE) {
        int s = el[e * 3 + 1] * RR + el[e * 3 + 2];
        int pos = segst[s] + atomicAdd(&cursor[s], 1);
        perm[pos] = e;
    }
}

// ---------------- A/B node-partial precompute (layer 0 only) ----------------

__global__ __launch_bounds__(256, 3) void abk_kernel(
    const ushort_t* __restrict__ hb16, const ushort_t* __restrict__ cab16,
    const ushort_t* __restrict__ pab, const float* __restrict__ b_e1,
    ushort_t* __restrict__ A16, ushort_t* __restrict__ B16)
{
    __shared__ ushort_t inbuf[32][296];
    __shared__ ushort_t obuf[32][520];
    const int tid = threadIdx.x, lane = tid & 63, w = tid >> 6;
    const int ar = lane & 15, aq = (lane >> 4) * 8, quad = lane >> 4;
    const int n0 = blockIdx.x * 32;
    const uint4 z4 = {0u, 0u, 0u, 0u};

    #pragma unroll
    for (int it = 0; it < 4; ++it) {
        int c = it * 256 + tid;
        int e = c >> 5, i4 = c & 31;
        int node = n0 + e;
        uint4 v = (node < NN) ? ((const uint4*)(hb16 + (size_t)node * 256))[i4] : z4;
        *(uint4*)&inbuf[e][i4 * 8] = v;
    }
    if (tid < 64) {
        int e = tid >> 1, i4 = tid & 1;
        int node = n0 + e;
        uint4 v = (node < NN) ? ((const uint4*)(cab16 + node * 16))[i4] : z4;
        *(uint4*)&inbuf[e][256 + i4 * 8] = v;
    } else if (tid < 128) {
        int c = tid - 64, e = c >> 1, i4 = c & 1;
        *(uint4*)&inbuf[e][272 + i4 * 8] = z4;
    }
    __syncthreads();

    const f32x4 Z = {0.f, 0.f, 0.f, 0.f};
    f32x4 acc[2][8];
    #pragma unroll
    for (int mt = 0; mt < 2; ++mt)
        #pragma unroll
        for (int jt = 0; jt < 8; ++jt) acc[mt][jt] = Z;
    for (int kt = 0; kt < 9; ++kt) {
        bf16x8 a0 = *(const bf16x8*)&inbuf[ar][kt * 32 + aq];
        bf16x8 a1 = *(const bf16x8*)&inbuf[16 + ar][kt * 32 + aq];
        #pragma unroll
        for (int jt = 0; jt < 8; ++jt) {
            bf16x8 b = *(const bf16x8*)(pab + ((size_t)(kt * 32 + w * 8 + jt) * 64 + lane) * 8);
            acc[0][jt] = __builtin_amdgcn_mfma_f32_16x16x32_bf16(a0, b, acc[0][jt], 0, 0, 0);
            acc[1][jt] = __builtin_amdgcn_mfma_f32_16x16x32_bf16(a1, b, acc[1][jt], 0, 0, 0);
        }
    }
    #pragma unroll
    for (int jt = 0; jt < 8; ++jt) {
        int n = w * 128 + jt * 16 + ar;
        float bias = (n < 256) ? b_e1[n] : 0.f;
        #pragma unroll
        for (int mt = 0; mt < 2; ++mt)
            #pragma unroll
            for (int r = 0; r < 4; ++r)
                obuf[mt * 16 + quad * 4 + r][n] = bf16u_n(acc[mt][jt][r] + bias);
    }
    __syncthreads();
    #pragma unroll
    for (int it = 0; it < 8; ++it) {
        int c = it * 256 + tid;
        int e = c >> 6, i4 = c & 63;
        int node = n0 + e;
        if (node < NN) {
            if (i4 < 32)
                *(uint4*)(A16 + (size_t)node * 256 + i4 * 8) = *(const uint4*)&obuf[e][i4 * 8];
            else
                *(uint4*)(B16 + (size_t)node * 256 + (i4 - 32) * 8) = *(const uint4*)&obuf[e][256 + (i4 - 32) * 8];
        }
    }
}

// ---------------- MFMA stage helper (32-edge M-tile) ----------------

template<int KT, int NTOT>
__device__ __forceinline__ void mfma_stage32(
    const ushort_t (&A)[32][584], int colOff,
    const ushort_t* __restrict__ Wp, int w, int lane,
    f32x4 (&acc)[2][4])
{
    const f32x4 Z = {0.f, 0.f, 0.f, 0.f};
    #pragma unroll
    for (int mt = 0; mt < 2; ++mt)
        #pragma unroll
        for (int j = 0; j < 4; ++j) acc[mt][j] = Z;
    const int ar = lane & 15, aq = (lane >> 4) * 8;
    for (int kt = 0; kt < KT; ++kt) {
        bf16x8 a0 = *(const bf16x8*)&A[ar][colOff + kt * 32 + aq];
        bf16x8 a1 = *(const bf16x8*)&A[16 + ar][colOff + kt * 32 + aq];
        #pragma unroll
        for (int j = 0; j < 4; ++j) {
            bf16x8 b = *(const bf16x8*)(Wp + ((size_t)(kt * NTOT + w * 4 + j) * 64 + lane) * 8);
            acc[0][j] = __builtin_amdgcn_mfma_f32_16x16x32_bf16(a0, b, acc[0][j], 0, 0, 0);
            acc[1][j] = __builtin_amdgcn_mfma_f32_16x16x32_bf16(a1, b, acc[1][j], 0, 0, 0);
        }
    }
}

// ---------------- fused edge kernel (32 sorted edges/block, 4 blk/CU) ----------

__global__ __launch_bounds__(256, 4) void edge_kernel(
    const int* __restrict__ el, const int* __restrict__ perm,
    const float* __restrict__ cw,
    const float* __restrict__ ew, const float* __restrict__ x,
    const ushort_t* __restrict__ A16, const ushort_t* __restrict__ B16,
    const float* __restrict__ W_rad, const float* __restrict__ b_rad,
    const ushort_t* __restrict__ pe1c,
    const ushort_t* __restrict__ pe2, const float* __restrict__ b_e2,
    const ushort_t* __restrict__ pc1, const float* __restrict__ b_c1,
    const ushort_t* __restrict__ pc2,
    ushort_t* __restrict__ mb16, float* __restrict__ xacc)
{
    // X = cols 0..255 (rad_feat in 0..31, later m), Y = cols 288..543 (S/t1/t2)
    __shared__ ushort_t abuf[32][584];
    __shared__ float radbuf[32][16];
    __shared__ int rowS[32], colS[32];
    __shared__ float ewS[32];

    const int tid = threadIdx.x, lane = tid & 63, w = tid >> 6;
    const int ar = lane & 15, aq = (lane >> 4) * 8, quad = lane >> 4;
    const int e0 = blockIdx.x * 32;

    if (tid < 32) {
        int eg = perm[e0 + tid];
        rowS[tid] = el[eg * 3 + 0];
        colS[tid] = el[eg * 3 + 1];
        ewS[tid]  = ew[eg];
    }
    __syncthreads();   // B1

    // ---- staging: S = A[row] + B[col] -> Y, radial -> radbuf ----
    #pragma unroll
    for (int it = 0; it < 4; ++it) {
        int c = it * 256 + tid;
        int e = c >> 5, i4 = c & 31;
        bf16x8 va = *(const bf16x8*)((const uint4*)(A16 + (size_t)rowS[e] * 256) + i4);
        bf16x8 vb = *(const bf16x8*)((const uint4*)(B16 + (size_t)colS[e] * 256) + i4);
        bf16x8 vs;
        #pragma unroll
        for (int j = 0; j < 8; ++j)
            vs[j] = (__bf16)((float)va[j] + (float)vb[j]);
        *(bf16x8*)&abuf[e][288 + i4 * 8] = vs;
    }
    #pragma unroll
    for (int it = 0; it < 2; ++it) {
        int t = it * 256 + tid;
        int e = t >> 4, ab = t & 15, a = ab >> 2, b = ab & 3;
        int row = rowS[e], col = colS[e];
        float d0 = x[row * 12 + a * 3 + 0] - x[col * 12 + b * 3 + 0];
        float d1 = x[row * 12 + a * 3 + 1] - x[col * 12 + b * 3 + 1];
        float d2 = x[row * 12 + a * 3 + 2] - x[col * 12 + b * 3 + 2];
        radbuf[e][ab] = (d0 * d0 + d1 * d1 + d2 * d2)
                      * cw[row * CCH + a] * cw[col * CCH + b];
    }
    __syncthreads();   // B2

    // rad_feat -> X cols 0..15, zero pad 16..31
    #pragma unroll
    for (int it = 0; it < 2; ++it) {
        int t = it * 256 + tid;
        int e = t >> 4, f = t & 15;
        float acc = b_rad[f];
        #pragma unroll
        for (int ab = 0; ab < 16; ++ab) acc += radbuf[e][ab] * W_rad[ab * 16 + f];
        abuf[e][f] = bf16u_m(silu_f(acc));
        abuf[e][16 + f] = 0;
    }
    __syncthreads();   // B3

    f32x4 acc[2][4];

    // ---- e1 residual: rad_feat @ W1c (KT=1), t1 = silu(S + acc) ----
    mfma_stage32<1, 16>(abuf, 0, pe1c, w, lane, acc);
    #pragma unroll
    for (int j = 0; j < 4; ++j) {
        int n = w * 64 + j * 16 + ar;
        #pragma unroll
        for (int mt = 0; mt < 2; ++mt)
            #pragma unroll
            for (int r = 0; r < 4; ++r) {
                int e = mt * 16 + quad * 4 + r;
                float s = ubf2f(abuf[e][288 + n]) + acc[mt][j][r];
                abuf[e][288 + n] = bf16u_m(silu_f(s));
            }
    }
    __syncthreads();   // B4

    // ---- e2: reads Y, writes m -> X ----
    mfma_stage32<8, 16>(abuf, 288, pe2, w, lane, acc);
    #pragma unroll
    for (int j = 0; j < 4; ++j) {
        int n = w * 64 + j * 16 + ar;
        float bj = b_e2[n];
        #pragma unroll
        for (int mt = 0; mt < 2; ++mt)
            #pragma unroll
            for (int r = 0; r < 4; ++r) {
                int e = mt * 16 + quad * 4 + r;
                abuf[e][n] = bf16u_m(silu_f(acc[mt][j][r] + bj) * ewS[e]);
            }
    }
    __syncthreads();   // B5

    // ---- store m rows to mb16 ----
    #pragma unroll
    for (int it = 0; it < 4; ++it) {
        int t = it * 256 + tid;
        int e = t >> 5, c = t & 31;
        *(uint4*)(mb16 + ((size_t)(e0 + e) * 256 + c * 8)) =
            *(const uint4*)&abuf[e][c * 8];
    }

    // ---- c1: reads X, writes t2 -> Y ----
    mfma_stage32<8, 16>(abuf, 0, pc1, w, lane, acc);
    #pragma unroll
    for (int j = 0; j < 4; ++j) {
        int n = w * 64 + j * 16 + ar;
        float bj = b_c1[n];
        #pragma unroll
        for (int mt = 0; mt < 2; ++mt)
            #pragma unroll
            for (int r = 0; r < 4; ++r)
                abuf[mt * 16 + quad * 4 + r][288 + n] = bf16u_m(silu_f(acc[mt][j][r] + bj));
    }
    __syncthreads();   // B6

    // ---- c2: waves 0,1 -> phi -> radbuf ----
    if (w < 2) {
        const f32x4 Z = {0.f, 0.f, 0.f, 0.f};
        f32x4 p = Z;
        #pragma unroll
        for (int kt = 0; kt < 8; ++kt) {
            bf16x8 a = *(const bf16x8*)&abuf[w * 16 + ar][288 + kt * 32 + aq];
            bf16x8 b = *(const bf16x8*)(pc2 + ((size_t)kt * 64 + lane) * 8);
            p = __builtin_amdgcn_mfma_f32_16x16x32_bf16(a, b, p, 0, 0, 0);
        }
        #pragma unroll
        for (int r = 0; r < 4; ++r)
            radbuf[w * 16 + quad * 4 + r][ar] = p[r];
    }
    __syncthreads();   // B7

    // ---- trans -> xacc ----
    for (int t = tid; t < 384; t += 256) {
        int e = t / 12, r = t - e * 12, a = r / 3, k = r - a * 3;
        int row = rowS[e], col = colS[e];
        float xr = x[row * 12 + a * 3 + k];
        float s = 0.f;
        #pragma unroll
        for (int b = 0; b < 4; ++b)
            s += (xr - x[col * 12 + b * 3 + k]) * radbuf[e][a * 4 + b];
        atomicAdd(&xacc[row * 12 + a * 3 + k], 0.25f * s);
    }
}

// ---------------- fused node kernel (segsum + n1 + n2 + LN + xout + next-AB) --
// Tail (pabn != null): computes A16/B16 for the NEXT layer from this block's
// just-computed h (bit-identical bf16 to hb16) -- replaces the layer-1 abk.
// Arena reuse: habuf (0..9472) and obuf (9472..26112) only live after the
// reduction barrier, when nbuf/tbuf/h2buf are dead.

__global__ __launch_bounds__(256, 4) void node_kernel(
    const ushort_t* __restrict__ mb16, const int* __restrict__ segst,
    const ushort_t* __restrict__ pn1, const float* __restrict__ b_n1,
    const ushort_t* __restrict__ pn2, const float* __restrict__ b_n2,
    const float* __restrict__ ln_g, const float* __restrict__ ln_b,
    float* __restrict__ h_out, ushort_t* __restrict__ hb16,
    const float* __restrict__ x_in, float* __restrict__ xacc,
    const float* __restrict__ deg, float* __restrict__ x_out,
    const ushort_t* __restrict__ cab16,
    const ushort_t* __restrict__ pabn, const float* __restrict__ b_e1n,
    ushort_t* __restrict__ A16, ushort_t* __restrict__ B16)
{
    __shared__ __align__(16) char arena[33024];
    __shared__ float redS[16][16], red2S[16][16], muS[16], rsS[16];
    ushort_t (*nbuf)[1032] = (ushort_t(*)[1032])arena;
    ushort_t (*tbuf)[264] = (ushort_t(*)[264])arena;             // 8448 B
    float (*h2buf)[264] = (float(*)[264])(arena + 8448);         // 16896 B
    ushort_t (*habuf)[296] = (ushort_t(*)[296])arena;            // 9472 B (post-reduction)
    ushort_t (*obuf)[520] = (ushort_t(*)[520])(arena + 9472);    // 16640 B (post-reduction)

    const int tid = threadIdx.x, lane = tid & 63, w = tid >> 6;
    const int n0 = blockIdx.x * 16;
    const int ar = lane & 15, aq = (lane >> 4) * 8, quad = lane >> 4;
    const f32x4 Z = {0.f, 0.f, 0.f, 0.f};

    // ---- xout + xacc re-zero for next layer ----
    if (tid < 192) {
        int ln = tid / 12, r = tid - ln * 12;
        int n = n0 + ln;
        float c = fmaxf(deg[n], 1.f);
        x_out[n * 12 + r] = x_in[n * 12 + r] + xacc[n * 12 + r] / c;
        xacc[n * 12 + r] = 0.f;
    }

    f32x4 acc[4] = {Z, Z, Z, Z};
    for (int chunk = 0; chunk < 2; ++chunk) {
        for (int ln = 0; ln < 4; ++ln) {
            int node = w * 4 + ln;
            int gnode = n0 + node;
            if (chunk == 0) {
                #pragma unroll
                for (int r = 0; r < 4; ++r) {
                    int s = gnode * RR + r;
                    int beg = segst[s], end = segst[s + 1];
                    float a0 = 0.f, a1 = 0.f, a2 = 0.f, a3 = 0.f;
                    for (int e = beg; e < end; ++e) {
                        ushort4 u = *(const ushort4*)(mb16 + (size_t)e * 256 + lane * 4);
                        a0 += ubf2f(u.x); a1 += ubf2f(u.y);
                        a2 += ubf2f(u.z); a3 += ubf2f(u.w);
                    }
                    ushort4 o;
                    o.x = bf16u_n(a0); o.y = bf16u_n(a1); o.z = bf16u_n(a2); o.w = bf16u_n(a3);
                    *(ushort4*)&nbuf[node][r * 256 + lane * 4] = o;
                }
            } else {
                #pragma unroll
                for (int r = 4; r < 7; ++r) {
                    int s = gnode * RR + r;
                    int beg = segst[s], end = segst[s + 1];
                    float a0 = 0.f, a1 = 0.f, a2 = 0.f, a3 = 0.f;
                    for (int e = beg; e < end; ++e) {
                        ushort4 u = *(const ushort4*)(mb16 + (size_t)e * 256 + lane * 4);
                        a0 += ubf2f(u.x); a1 += ubf2f(u.y);
                        a2 += ubf2f(u.z); a3 += ubf2f(u.w);
                    }
                    ushort4 o;
                    o.x = bf16u_n(a0); o.y = bf16u_n(a1); o.z = bf16u_n(a2); o.w = bf16u_n(a3);
                    *(ushort4*)&nbuf[node][(r - 4) * 256 + lane * 4] = o;
                }
                *(ushort4*)&nbuf[node][768 + lane * 4] =
                    *(const ushort4*)(hb16 + (size_t)gnode * 256 + lane * 4);
            }
        }
        __syncthreads();
        for (int kt = 0; kt < 32; ++kt) {
            bf16x8 a = *(const bf16x8*)&nbuf[ar][kt * 32 + aq];
            int ktg = chunk * 32 + kt;
            #pragma unroll
            for (int j = 0; j < 4; ++j) {
                bf16x8 b = *(const bf16x8*)(pn1 + ((size_t)(ktg * 16 + w * 4 + j) * 64 + lane) * 8);
                acc[j] = __builtin_amdgcn_mfma_f32_16x16x32_bf16(a, b, acc[j], 0, 0, 0);
            }
        }
        __syncthreads();
    }
    #pragma unroll
    for (int j = 0; j < 4; ++j) {
        int n = w * 64 + j * 16 + ar;
        float bj = b_n1[n];
        #pragma unroll
        for (int r = 0; r < 4; ++r)
            tbuf[(lane >> 4) * 4 + r][n] = bf16u_n(silu_f(acc[j][r] + bj));
    }
    __syncthreads();
    f32x4 acc2[4] = {Z, Z, Z, Z};
    for (int kt = 0; kt < 8; ++kt) {
        bf16x8 a = *(const bf16x8*)&tbuf[ar][kt * 32 + aq];
        #pragma unroll
        for (int j = 0; j < 4; ++j) {
            bf16x8 b = *(const bf16x8*)(pn2 + ((size_t)(kt * 16 + w * 4 + j) * 64 + lane) * 8);
            acc2[j] = __builtin_amdgcn_mfma_f32_16x16x32_bf16(a, b, acc2[j], 0, 0, 0);
        }
    }
    float hv[4][4];
    #pragma unroll
    for (int j = 0; j < 4; ++j) {
        int n = w * 64 + j * 16 + ar;
        float bj = b_n2[n];
        #pragma unroll
        for (int r = 0; r < 4; ++r) {
            hv[j][r] = acc2[j][r] + bj;
            h2buf[(lane >> 4) * 4 + r][n] = hv[j][r];
        }
    }
    __syncthreads();
    {
        int node = tid >> 4, c = tid & 15;
        float s = 0.f, s2 = 0.f;
        #pragma unroll
        for (int i = 0; i < 16; ++i) {
            float v = h2buf[node][c * 16 + i];
            s += v; s2 += v * v;
        }
        redS[node][c] = s; red2S[node][c] = s2;
    }
    __syncthreads();
    if (tid < 16) {
        float s = 0.f, s2 = 0.f;
        #pragma unroll
        for (int c = 0; c < 16; ++c) { s += redS[tid][c]; s2 += red2S[tid][c]; }
        float mu = s * (1.f / 256.f);
        muS[tid] = mu;
        rsS[tid] = rsqrtf(s2 * (1.f / 256.f) - mu * mu + EPSV);
    }
    __syncthreads();   // after this barrier, nbuf/tbuf/h2buf are dead
    #pragma unroll
    for (int j = 0; j < 4; ++j) {
        int n = w * 64 + j * 16 + ar;
        float g = ln_g[n], bb = ln_b[n];
        #pragma unroll
        for (int r = 0; r < 4; ++r) {
            int row = (lane >> 4) * 4 + r;
            float v = (hv[j][r] - muS[row]) * rsS[row] * g + bb;
            if (h_out) h_out[(size_t)(n0 + row) * HH + n] = v;
            ushort_t hb = bf16u_n(v);
            hb16[(size_t)(n0 + row) * HH + n] = hb;
            if (pabn) habuf[row][n] = hb;       // mirror for next-layer AB GEMM
        }
    }

    // ---- next-layer A/B partials (replaces abk for layer l+1) ----
    if (pabn) {
        if (tid < 256) {
            int node = tid >> 4, f = tid & 15;
            habuf[node][256 + f] = cab16[(n0 + node) * 16 + f];
            habuf[node][272 + f] = 0;
        }
        __syncthreads();
        f32x4 pacc[8] = {Z, Z, Z, Z, Z, Z, Z, Z};
        for (int kt = 0; kt < 9; ++kt) {
            bf16x8 a = *(const bf16x8*)&habuf[ar][kt * 32 + aq];
            #pragma unroll
            for (int jt = 0; jt < 8; ++jt) {
                bf16x8 b = *(const bf16x8*)(pabn + ((size_t)(kt * 32 + w * 8 + jt) * 64 + lane) * 8);
                pacc[jt] = __builtin_amdgcn_mfma_f32_16x16x32_bf16(a, b, pacc[jt], 0, 0, 0);
            }
        }
        #pragma unroll
        for (int jt = 0; jt < 8; ++jt) {
            int n = w * 128 + jt * 16 + ar;
            float bias = (n < 256) ? b_e1n[n] : 0.f;
            #pragma unroll
            for (int r = 0; r < 4; ++r)
                obuf[quad * 4 + r][n] = bf16u_n(pacc[jt][r] + bias);
        }
        __syncthreads();
        #pragma unroll
        for (int it = 0; it < 4; ++it) {
            int c = it * 256 + tid;           // 1024 uint4 = 16 nodes x 64
            int node = c >> 6, i4 = c & 63;
            if (i4 < 32)
                *(uint4*)(A16 + (size_t)(n0 + node) * 256 + i4 * 8) =
                    *(const uint4*)&obuf[node][i4 * 8];
            else
                *(uint4*)(B16 + (size_t)(n0 + node) * 256 + (i4 - 32) * 8) =
                    *(const uint4*)&obuf[node][256 + (i4 - 32) * 8];
        }
    }
}

// ---------------- launcher ----------------

extern "C" void kernel_launch(void* const* d_in, const int* in_sizes, int n_in,
                              void* d_out, int out_size, void* d_ws, size_t ws_size,
                              hipStream_t stream)
{
    const float* input  = (const float*)d_in[0];
    const float* coords = (const float*)d_in[1];
    const float* cattr  = (const float*)d_in[2];
    const float* cwts   = (const float*)d_in[3];
    const float* ewts   = (const float*)d_in[4];
    const int*   elist  = (const int*)d_in[5];
    const float* W_rad  = (const float*)d_in[6];
    const float* b_rad  = (const float*)d_in[7];
    const float* W_e1   = (const float*)d_in[8];
    const float* b_e1   = (const float*)d_in[9];
    const float* W_e2   = (const float*)d_in[10];
    const float* b_e2   = (const float*)d_in[11];
    const float* W_c1   = (const float*)d_in[12];
    const float* b_c1   = (const float*)d_in[13];
    const float* W_c2   = (const float*)d_in[14];
    const float* W_n1   = (const float*)d_in[15];
    const float* b_n1   = (const float*)d_in[16];
    const float* W_n2   = (const float*)d_in[17];
    const float* b_n2   = (const float*)d_in[18];
    const float* ln_g   = (const float*)d_in[19];
    const float* ln_b   = (const float*)d_in[20];

    float* wsf  = (float*)d_ws;
    float* deg  = wsf;                    // 10000
    float* xacc = deg + 10000;            // 120000
    float* xbuf = xacc + 120000;          // 120000
    int* ip     = (int*)(xbuf + 120000);
    int* hist   = ip;                     // 70000
    int* pscan  = hist + 70000;           // 70000
    int* cursor = pscan + 70000;          // 70000
    int* segst  = cursor + 70000;         // 70001
    int* bsum   = segst + 70001;          // 512
    int* bofs   = bsum + 512;             // 512
    int* perm   = bofs + 512;             // 160000
    ushort_t* up = (ushort_t*)(((uintptr_t)(perm + 160000) + 15) & ~(uintptr_t)15);
    ushort_t* hb16  = up;                 // 2,560,000
    ushort_t* cab16 = hb16 + 2560000;     // 160,000
    ushort_t* mb16  = cab16 + 160000;     // 40,960,000
    ushort_t* A16   = mb16 + 40960000;    // 2,560,000
    ushort_t* B16   = A16 + 2560000;      // 2,560,000
    ushort_t* pab   = B16 + 2560000;      // 2 x 147456
    ushort_t* pe1c  = pab + 294912;       // 2 x 8192
    ushort_t* pe2   = pe1c + 16384;       // 2 x 65536
    ushort_t* pc1   = pe2 + 131072;       // 2 x 65536
    ushort_t* pc2   = pc1 + 131072;       // 2 x 4096
    ushort_t* pn1   = pc2 + 8192;         // 2 x 524288
    ushort_t* pn2   = pn1 + 1048576;      // 2 x 65536

    prep_kernel<<<12542, 256, 0, stream>>>(
        input, hb16, cattr, cwts, cab16, hist, cursor, deg, xacc,
        W_e1, W_e2, W_c1, W_c2, W_n1, W_n2,
        pab, pe1c, pe2, pc1, pc2, pn1, pn2);

    histdeg_kernel<<<(EE + 255) / 256, 256, 0, stream>>>(elist, hist, deg);
    scan1_kernel<<<SCB, 256, 0, stream>>>(hist, pscan, bsum);
    scan2_kernel<<<1, 256, 0, stream>>>(bsum, bofs, SCB);
    scan3_kernel<<<SCB, 256, 0, stream>>>(pscan, bofs, segst);
    scatter_kernel<<<(EE + 255) / 256, 256, 0, stream>>>(elist, segst, cursor, perm);

    // layer-0 A/B partials
    abk_kernel<<<(NN + 31) / 32, 256, 0, stream>>>(
        hb16, cab16, pab, b_e1, A16, B16);

    for (int l = 0; l < 2; ++l) {
        const float* x_in = (l == 0) ? coords : xbuf;
        float* h_out = (l == 0) ? nullptr : (float*)d_out;  // layer0 fp32 h never read
        float* x_out = (l == 0) ? xbuf : ((float*)d_out + (size_t)NN * HH);

        edge_kernel<<<EE / 32, 256, 0, stream>>>(
            elist, perm, cwts, ewts, x_in, A16, B16,
            W_rad + l * 256, b_rad + l * 16,
            pe1c + (size_t)l * 8192,
            pe2 + (size_t)l * 65536,  b_e2 + l * HH,
            pc1 + (size_t)l * 65536,  b_c1 + l * HH,
            pc2 + (size_t)l * 4096,
            mb16, xacc);

        node_kernel<<<NN / 16, 256, 0, stream>>>(
            mb16, segst,
            pn1 + (size_t)l * 524288, b_n1 + l * HH,
            pn2 + (size_t)l * 65536,  b_n2 + l * HH,
            ln_g + l * HH, ln_b + l * HH,
            h_out, hb16,
            x_in, xacc, deg, x_out,
            cab16,
            (l == 0) ? (pab + 147456) : nullptr,
            (l == 0) ? (b_e1 + HH) : nullptr,
            A16, B16);
    }
}